// Round 12
// baseline (342.955 us; speedup 1.0000x reference)
//
#include <hip/hip_runtime.h>
#include <hip/hip_bf16.h>

#define Bn 8
#define Cc 64     // Cin = Cout
#define Hh 256
#define Ww 256
#define Ss 512

// LDS geometry (u32 units): cell = 16 ci-pairs + 4 pad = 20 u32 (40 shorts,
// 16B-aligned cells). Row = 66 cells = 1320 + 1 pad = 1321 u32 (mod 4 = 1 so
// the 4 staging quad-groups land in disjoint bank-residue classes).
// phi-XOR swizzle: u32 idx = r*1321 + c*20 + (cp ^ (((c>>3)&3)<<2)).
//  - reads (ds_read_b128 at quad-block q): XOR permutes q-blocks within the
//    cell -> start-bank multiset unchanged: {20*l15} (+){0,4,8,12} tiles all
//    32 banks at exactly 8 words/bank (perfect).
//  - writes (u32 per cell, 16 cg lanes/quad-group): bank = 16(cg&1) +
//    4((cg>>1)&3) + const -> 8 banks x 2 lanes = 2-way (free, m136).
#define LROW_U  1321
#define LROW_S  2642
#define LCELL_S 40

typedef __attribute__((ext_vector_type(8))) short short8;   // 8 bf16 (4 VGPRs)
typedef __attribute__((ext_vector_type(4))) float floatx4;  // MFMA C/D

// fp32 -> bf16 bits, round-to-nearest-even (scalar path, k_weights)
__device__ __forceinline__ unsigned f2bf_bits(float f) {
    unsigned u = __float_as_uint(f);
    return (u + 0x7FFFu + ((u >> 16) & 1u)) >> 16;
}

// two fp32 -> packed 2x bf16 (lo in low 16 bits) via v_cvt_pk_bf16_f32
__device__ __forceinline__ unsigned pack_bf2(float lo, float hi) {
    __hip_bfloat162 p = __float22bfloat162_rn(make_float2(lo, hi));
    union { __hip_bfloat162 h; unsigned u; } cv;
    cv.h = p;
    return cv.u;
}

// ---------------------------------------------------------------------------
// Kernel 1: style linear  y[b][c] = lin_b[c] + (1/sqrt(S)) * sum_s w[b,s]*lin_w[c,s]
// ---------------------------------------------------------------------------
__global__ void k_style(const float* __restrict__ w,
                        const float* __restrict__ lin_w,
                        const float* __restrict__ lin_b,
                        float* __restrict__ y) {
    int bc = blockIdx.x;          // b*64 + c
    int b = bc >> 6, c = bc & 63;
    int lane = threadIdx.x;       // 64 threads
    float acc = 0.f;
#pragma unroll
    for (int i = 0; i < Ss / 64; ++i) {
        int s = i * 64 + lane;
        acc += w[b * Ss + s] * lin_w[c * Ss + s];
    }
#pragma unroll
    for (int off = 32; off >= 1; off >>= 1) acc += __shfl_xor(acc, off, 64);
    if (lane == 0)
        y[bc] = acc * 0.04419417382415922f /* 1/sqrt(512) */ + lin_b[c];
}

// ---------------------------------------------------------------------------
// Kernel 2: modulate + demodulate; emit bf16 weights in MFMA A-fragment
// friendly layout:  wt[b][slab(2)][tap(9)][co(64)][ci_lo(32)]
// ---------------------------------------------------------------------------
__global__ void k_weights(const float* __restrict__ conv_w,
                          const float* __restrict__ y,
                          short* __restrict__ wt) {
    int bco = blockIdx.x;          // b*64 + co
    int b = bco >> 6, co = bco & 63;
    int ci = threadIdx.x;          // 64 threads = ci
    const float conv_scale = 1.0f / 24.0f;   // 1/sqrt(64*9)
    float yv = y[b * Cc + ci] * conv_scale;
    float wv[9];
    float ss = 0.f;
#pragma unroll
    for (int k = 0; k < 9; ++k) {
        float v = conv_w[(co * Cc + ci) * 9 + k] * yv;
        wv[k] = v;
        ss += v * v;
    }
#pragma unroll
    for (int off = 32; off >= 1; off >>= 1) ss += __shfl_xor(ss, off, 64);
    float demod = rsqrtf(ss + 1e-8f);
    int s = ci >> 5, cl = ci & 31;
#pragma unroll
    for (int t = 0; t < 9; ++t)
        wt[(((b * 2 + s) * 9 + t) * Cc + co) * 32 + cl] =
            (short)f2bf_bits(wv[t] * demod);
}

// ---------------------------------------------------------------------------
// Kernel 3: implicit-GEMM conv via 9 tap-shifted GEMMs on bf16 MFMA.
// R7 (counter-driven post-mortem of R6: BANK_CONFLICT 10.27M was READ-side --
// cell=21 u32 gives clustered 21*l15 start banks -- and the R6 2m-split
// doubled ds_read count by halving bfr reuse):
//  * wave split 4m x 2nt: acc[4][2] (32 AGPR), afr[4], bfr[2]. ds_read_b128
//    halved (16/block-tap); each bfr feeds 4 MFMAs. afr = 4 coalesced 1KB
//    L1-hit loads/wave-tap (wt slab 36KB is XCD-L2/L1 resident via swizzle).
//  * LDS cell back to 20 u32 (perfect read banks) + phi-XOR write fix
//    (see defines above): reads stay perfect, writes 8-way -> 2-way.
//  * 512 threads, 2-phase slab staging, T1 XCD swizzle, s=0 barrier
//    elision kept from R6.
// MFMA 16x16x32 layouts (HW-verified): A[m=l15][k=quad*8+j],
// B[k=quad*8+j][n=l15], D row=quad*4+reg, col=l15.
// ---------------------------------------------------------------------------
__global__ __launch_bounds__(512, 4) void k_mfma(
    const float* __restrict__ x,
    const short* __restrict__ wt,
    const float* __restrict__ noise,
    const float* __restrict__ nw_p,
    const float* __restrict__ act_bias,
    float* __restrict__ out) {
    __shared__ short xs[6 * LROW_S];   // 31704 B

    const int tid = threadIdx.x;
    const int wave = tid >> 6, lane = tid & 63;
    const int l15 = lane & 15, quad = lane >> 4;
    const int wr = wave >> 1;          // h row 0..3
    const int n0 = (wave & 1) * 2;     // n-tile pair: {n0, n0+1}

    // T1 XCD-chunked swizzle: each XCD gets one contiguous b.
    const int bid = blockIdx.x;
    const int swz = (bid & 7) * 256 + (bid >> 3);   // bijective, 2048%8==0
    const int b = swz >> 8;                          // 0..7
    const int rem = swz & 255;
    const int w0 = (rem & 3) * 64, h0 = (rem >> 2) * 4;

    // staging decomposition, fixed per thread
    const int cg = tid & 15;            // col group: c = 1 + 4*cg
    const int rc0 = tid >> 4;           // 0..31, walks +32/iter over 0..95

    floatx4 acc[4][2];   // [m-tile][n-tile within pair]
#pragma unroll
    for (int mt = 0; mt < 4; ++mt)
#pragma unroll
        for (int ni = 0; ni < 2; ++ni)
            acc[mt][ni] = (floatx4){0.f, 0.f, 0.f, 0.f};

    unsigned* const xsu = (unsigned*)xs;

    for (int s = 0; s < 2; ++s) {
        if (s) __syncthreads();   // xs reuse: previous slab's readers done

        // ---- interior: 96 (r,cp) rows x 16 aligned float4 col-groups
        {
            int r = rc0, cp = 0;         // r = rc0 % 6, cp = rc0 / 6
            if (r >= 6) { r -= 6; cp = 1; }
            if (r >= 6) { r -= 6; cp = 2; }
            if (r >= 6) { r -= 6; cp = 3; }
            if (r >= 6) { r -= 6; cp = 4; }
            if (r >= 6) { r -= 6; cp = 5; }
            const int cbase = 1 + cg * 4;    // 1..61
#pragma unroll
            for (int it = 0; it < 3; ++it) {
                const int gh = h0 + r - 1;
                float4 lo4 = make_float4(0.f, 0.f, 0.f, 0.f);
                float4 hi4 = make_float4(0.f, 0.f, 0.f, 0.f);
                if ((unsigned)gh < (unsigned)Hh) {
                    const float* xp = x +
                        (((size_t)(b * Cc + s * 32 + cp * 2)) << 16) +
                        gh * Ww + (w0 + cg * 4);          // 16B aligned
                    lo4 = *(const float4*)xp;
                    hi4 = *(const float4*)(xp + Hh * Ww);
                }
                const float lov[4] = {lo4.x, lo4.y, lo4.z, lo4.w};
                const float hiv[4] = {hi4.x, hi4.y, hi4.z, hi4.w};
#pragma unroll
                for (int j = 0; j < 4; ++j) {
                    const int c = cbase + j;
                    xsu[r * LROW_U + c * 20 +
                        (cp ^ ((((unsigned)c >> 3) & 3) << 2))] =
                        pack_bf2(lov[j], hiv[j]);
                }
                r += 2; cp += 5;                 // rc += 32 (32 = 5*6+2)
                if (r >= 6) { r -= 6; ++cp; }
            }
        }
        // ---- halo cols c=0 and c=65 (phi=0 for both): 96 rows x 2, scalar
        if (tid < 192) {
            const int side = tid & 1;
            const int rc = tid >> 1;             // 0..95
            const int hr = rc % 6, hcp = rc / 6;
            const int gh = h0 + hr - 1;
            const int gw = side ? (w0 + 64) : (w0 - 1);
            float lo = 0.f, hi = 0.f;
            if ((unsigned)gh < (unsigned)Hh && (unsigned)gw < (unsigned)Ww) {
                const float* xp = x +
                    (((size_t)(b * Cc + s * 32 + hcp * 2)) << 16) +
                    gh * Ww + gw;
                lo = xp[0];
                hi = xp[Hh * Ww];
            }
            xsu[hr * LROW_U + (side ? 65 : 0) * 20 + hcp] = pack_bf2(lo, hi);
        }
        __syncthreads();

        const short* wbase = wt + (size_t)((b * 2 + s) * 9) * Cc * 32;
#pragma unroll
        for (int t = 0; t < 9; ++t) {
            const int dr = t / 3, dc = t % 3;
            short8 bfr[2];
#pragma unroll
            for (int ni = 0; ni < 2; ++ni) {
                const int c = (n0 + ni) * 16 + l15 + dc;
                bfr[ni] = *(const short8*)(xs + (wr + dr) * LROW_S + c * LCELL_S +
                    ((quad * 8) ^ ((((unsigned)c >> 3) & 3) << 3)));
            }
            short8 afr[4];
#pragma unroll
            for (int mt = 0; mt < 4; ++mt)
                afr[mt] = *(const short8*)(wbase +
                    ((t * Cc + mt * 16 + l15) * 32 + quad * 8));
#pragma unroll
            for (int mt = 0; mt < 4; ++mt)
#pragma unroll
                for (int ni = 0; ni < 2; ++ni)
                    acc[mt][ni] = __builtin_amdgcn_mfma_f32_16x16x32_bf16(
                        afr[mt], bfr[ni], acc[mt][ni], 0, 0, 0);
        }
    }

    // ---- epilogue: noise + bias + leaky_relu * sqrt(2), fp32 store
    const int h = h0 + wr;
    const float nw = nw_p[0];
    float nz[2];
#pragma unroll
    for (int ni = 0; ni < 2; ++ni)
        nz[ni] = nw * noise[((size_t)b * Hh + h) * Ww + w0 + (n0 + ni) * 16 + l15];
#pragma unroll
    for (int mt = 0; mt < 4; ++mt) {
#pragma unroll
        for (int reg = 0; reg < 4; ++reg) {
            int co = mt * 16 + quad * 4 + reg;
            float bias = act_bias[co];
#pragma unroll
            for (int ni = 0; ni < 2; ++ni) {
                float v = acc[mt][ni][reg] + nz[ni] + bias;
                v = (v > 0.f ? v : 0.2f * v) * 1.41421356237f;
                out[(((size_t)(b * Cc + co)) * Hh + h) * Ww +
                    w0 + (n0 + ni) * 16 + l15] = v;
            }
        }
    }
}

extern "C" void kernel_launch(void* const* d_in, const int* in_sizes, int n_in,
                              void* d_out, int out_size, void* d_ws, size_t ws_size,
                              hipStream_t stream) {
    const float* x        = (const float*)d_in[0];
    const float* w        = (const float*)d_in[1];
    const float* noise    = (const float*)d_in[2];
    const float* lin_w    = (const float*)d_in[3];
    const float* lin_b    = (const float*)d_in[4];
    const float* conv_w   = (const float*)d_in[5];
    const float* nw_p     = (const float*)d_in[6];
    const float* act_bias = (const float*)d_in[7];

    float* y  = (float*)d_ws;                       // 512 floats
    short* wtb = (short*)((char*)d_ws + 4096);      // 8*2*9*64*32 bf16 = 576 KB

    k_style<<<Bn * Cc, 64, 0, stream>>>(w, lin_w, lin_b, y);
    k_weights<<<Bn * Cc, 64, 0, stream>>>(conv_w, y, wtb);

    k_mfma<<<dim3(2048, 1, 1), 512, 0, stream>>>(x, wtb, noise, nw_p, act_bias,
                                                 (float*)d_out);
}

// Round 13
// 317.286 us; speedup vs baseline: 1.0809x; 1.0809x over previous
//
#include <hip/hip_runtime.h>
#include <hip/hip_bf16.h>

#define Bn 8
#define Cc 64     // Cin = Cout
#define Hh 256
#define Ww 256
#define Ss 512

// LDS geometry (u32 units): cell = 16 ci-pairs + 4 pad = 20 u32 = 80 B
// (16B-aligned cells); row = 66 cells = 1320 u32 = 5280 B == 0 mod 16.
// ALL ds_read_b128 addresses are provably 16B-aligned (every term is a
// multiple of 16B) -> compiler emits true b128 (R5-verified: aligned rows
// gave read-conflict-free ds_read_b128; R6/R7's rows==4 mod 16 forced
// split b32s = the 10-18M conflict regression).
// phi-XOR: f(c) = (c>>3)&3; u32 idx = r*1320 + c*20 + (cp ^ (f<<2)).
//  - writes (u32/lane): quad-group banks 16(cg&1) + (cp^4f) + const ->
//    8 distinct banks x 2 lanes = 2-way free (m136).
//  - reads (b128 of block q): fetches u32s 4*(q^f)+k -> un-XOR yields ci
//    8q..8q+7; start banks = multiples of 4, 4 lanes/start per 32-lane
//    phase -> uniform 4 accesses/bank = conflict-free.
//  - halo cols 0,65: f=0 both ((65>>3)&3 == 0) -> plain cp.
#define LROW_U  1320
#define LROW_S  2640
#define LCELL_S 40

typedef __attribute__((ext_vector_type(8))) short short8;   // 8 bf16 (4 VGPRs)
typedef __attribute__((ext_vector_type(4))) float floatx4;  // MFMA C/D

// fp32 -> bf16 bits, round-to-nearest-even (scalar path, k_weights)
__device__ __forceinline__ unsigned f2bf_bits(float f) {
    unsigned u = __float_as_uint(f);
    return (u + 0x7FFFu + ((u >> 16) & 1u)) >> 16;
}

// two fp32 -> packed 2x bf16 (lo in low 16 bits) via v_cvt_pk_bf16_f32
__device__ __forceinline__ unsigned pack_bf2(float lo, float hi) {
    __hip_bfloat162 p = __float22bfloat162_rn(make_float2(lo, hi));
    union { __hip_bfloat162 h; unsigned u; } cv;
    cv.h = p;
    return cv.u;
}

// ---------------------------------------------------------------------------
// Kernel 1: style linear  y[b][c] = lin_b[c] + (1/sqrt(S)) * sum_s w[b,s]*lin_w[c,s]
// ---------------------------------------------------------------------------
__global__ void k_style(const float* __restrict__ w,
                        const float* __restrict__ lin_w,
                        const float* __restrict__ lin_b,
                        float* __restrict__ y) {
    int bc = blockIdx.x;          // b*64 + c
    int b = bc >> 6, c = bc & 63;
    int lane = threadIdx.x;       // 64 threads
    float acc = 0.f;
#pragma unroll
    for (int i = 0; i < Ss / 64; ++i) {
        int s = i * 64 + lane;
        acc += w[b * Ss + s] * lin_w[c * Ss + s];
    }
#pragma unroll
    for (int off = 32; off >= 1; off >>= 1) acc += __shfl_xor(acc, off, 64);
    if (lane == 0)
        y[bc] = acc * 0.04419417382415922f /* 1/sqrt(512) */ + lin_b[c];
}

// ---------------------------------------------------------------------------
// Kernel 2: modulate + demodulate; emit bf16 weights in MFMA A-fragment
// friendly layout:  wt[b][slab(2)][tap(9)][co(64)][ci_lo(32)]
// ---------------------------------------------------------------------------
__global__ void k_weights(const float* __restrict__ conv_w,
                          const float* __restrict__ y,
                          short* __restrict__ wt) {
    int bco = blockIdx.x;          // b*64 + co
    int b = bco >> 6, co = bco & 63;
    int ci = threadIdx.x;          // 64 threads = ci
    const float conv_scale = 1.0f / 24.0f;   // 1/sqrt(64*9)
    float yv = y[b * Cc + ci] * conv_scale;
    float wv[9];
    float ss = 0.f;
#pragma unroll
    for (int k = 0; k < 9; ++k) {
        float v = conv_w[(co * Cc + ci) * 9 + k] * yv;
        wv[k] = v;
        ss += v * v;
    }
#pragma unroll
    for (int off = 32; off >= 1; off >>= 1) ss += __shfl_xor(ss, off, 64);
    float demod = rsqrtf(ss + 1e-8f);
    int s = ci >> 5, cl = ci & 31;
#pragma unroll
    for (int t = 0; t < 9; ++t)
        wt[(((b * 2 + s) * 9 + t) * Cc + co) * 32 + cl] =
            (short)f2bf_bits(wv[t] * demod);
}

// ---------------------------------------------------------------------------
// Kernel 3: implicit-GEMM conv via 9 tap-shifted GEMMs on bf16 MFMA.
// R12 recombination of MEASURED-good parts (R12 counters: R7's 18.1M
// conflicts = unaligned-split b128 from row stride==4 mod 16; +40MB FETCH
// from doubled afr loads; +98MB WRITE from 32-col wave rows):
//  * R5 LDS geometry: row 1320 u32 (16B-aligned b128, uniform read banks).
//  * NEW phi-XOR on cp (defines above): kills R5's 8-way write conflict
//    (its 7.9M residual) without touching read alignment/uniformity.
//  * R6 wave split 2m x 4nt: acc[2][4] (32 AGPR), afr[2], bfr[4] ->
//    16 afr global loads/block-tap (FETCH back to ~69MB) and 64-col
//    epilogue rows (WRITE back to ~131MB).
//  * 512 threads, 2-phase slab staging, T1 XCD swizzle, s=0 barrier
//    elision kept.
// MFMA 16x16x32 layouts (HW-verified): A[m=l15][k=quad*8+j],
// B[k=quad*8+j][n=l15], D row=quad*4+reg, col=l15.
// ---------------------------------------------------------------------------
__global__ __launch_bounds__(512, 4) void k_mfma(
    const float* __restrict__ x,
    const short* __restrict__ wt,
    const float* __restrict__ noise,
    const float* __restrict__ nw_p,
    const float* __restrict__ act_bias,
    float* __restrict__ out) {
    __shared__ short xs[6 * LROW_S];   // 31680 B

    const int tid = threadIdx.x;
    const int wave = tid >> 6, lane = tid & 63;
    const int l15 = lane & 15, quad = lane >> 4;
    const int wr = wave >> 1;        // h row 0..3
    const int wm = wave & 1;         // m-half 0..1

    // T1 XCD-chunked swizzle: each XCD gets one contiguous b.
    const int bid = blockIdx.x;
    const int swz = (bid & 7) * 256 + (bid >> 3);   // bijective, 2048%8==0
    const int b = swz >> 8;                          // 0..7
    const int rem = swz & 255;
    const int w0 = (rem & 3) * 64, h0 = (rem >> 2) * 4;

    // staging decomposition, fixed per thread
    const int cg = tid & 15;            // col group: c = 1 + 4*cg
    const int rc0 = tid >> 4;           // 0..31, walks +32/iter over 0..95

    floatx4 acc[2][4];   // [m-tile within half][n-tile]
#pragma unroll
    for (int mi = 0; mi < 2; ++mi)
#pragma unroll
        for (int nt = 0; nt < 4; ++nt)
            acc[mi][nt] = (floatx4){0.f, 0.f, 0.f, 0.f};

    unsigned* const xsu = (unsigned*)xs;

    for (int s = 0; s < 2; ++s) {
        if (s) __syncthreads();   // xs reuse: previous slab's readers done

        // ---- interior: 96 (r,cp) rows x 16 aligned float4 col-groups
        {
            int r = rc0, cp = 0;         // r = rc0 % 6, cp = rc0 / 6
            if (r >= 6) { r -= 6; cp = 1; }
            if (r >= 6) { r -= 6; cp = 2; }
            if (r >= 6) { r -= 6; cp = 3; }
            if (r >= 6) { r -= 6; cp = 4; }
            if (r >= 6) { r -= 6; cp = 5; }
            const int cbase = 1 + cg * 4;    // 1..61
#pragma unroll
            for (int it = 0; it < 3; ++it) {
                const int gh = h0 + r - 1;
                float4 lo4 = make_float4(0.f, 0.f, 0.f, 0.f);
                float4 hi4 = make_float4(0.f, 0.f, 0.f, 0.f);
                if ((unsigned)gh < (unsigned)Hh) {
                    const float* xp = x +
                        (((size_t)(b * Cc + s * 32 + cp * 2)) << 16) +
                        gh * Ww + (w0 + cg * 4);          // 16B aligned
                    lo4 = *(const float4*)xp;
                    hi4 = *(const float4*)(xp + Hh * Ww);
                }
                const float lov[4] = {lo4.x, lo4.y, lo4.z, lo4.w};
                const float hiv[4] = {hi4.x, hi4.y, hi4.z, hi4.w};
#pragma unroll
                for (int j = 0; j < 4; ++j) {
                    const int c = cbase + j;
                    xsu[r * LROW_U + c * 20 +
                        (cp ^ ((((unsigned)c >> 3) & 3) << 2))] =
                        pack_bf2(lov[j], hiv[j]);
                }
                r += 2; cp += 5;                 // rc += 32 (32 = 5*6+2)
                if (r >= 6) { r -= 6; ++cp; }
            }
        }
        // ---- halo cols c=0 and c=65 (phi=0 for both): 96 rows x 2, scalar
        if (tid < 192) {
            const int side = tid & 1;
            const int rc = tid >> 1;             // 0..95
            const int hr = rc % 6, hcp = rc / 6;
            const int gh = h0 + hr - 1;
            const int gw = side ? (w0 + 64) : (w0 - 1);
            float lo = 0.f, hi = 0.f;
            if ((unsigned)gh < (unsigned)Hh && (unsigned)gw < (unsigned)Ww) {
                const float* xp = x +
                    (((size_t)(b * Cc + s * 32 + hcp * 2)) << 16) +
                    gh * Ww + gw;
                lo = xp[0];
                hi = xp[Hh * Ww];
            }
            xsu[hr * LROW_U + (side ? 65 : 0) * 20 + hcp] = pack_bf2(lo, hi);
        }
        __syncthreads();

        const short* wbase = wt + (size_t)((b * 2 + s) * 9) * Cc * 32;
#pragma unroll
        for (int t = 0; t < 9; ++t) {
            const int dr = t / 3, dc = t % 3;
            short8 bfr[4];
#pragma unroll
            for (int nt = 0; nt < 4; ++nt) {
                const int c = nt * 16 + l15 + dc;
                bfr[nt] = *(const short8*)(xs + (wr + dr) * LROW_S + c * LCELL_S +
                    ((quad * 8) ^ ((((unsigned)c >> 3) & 3) << 3)));
            }
            short8 afr[2];
#pragma unroll
            for (int mi = 0; mi < 2; ++mi)
                afr[mi] = *(const short8*)(wbase +
                    ((t * Cc + (wm * 2 + mi) * 16 + l15) * 32 + quad * 8));
#pragma unroll
            for (int mi = 0; mi < 2; ++mi)
#pragma unroll
                for (int nt = 0; nt < 4; ++nt)
                    acc[mi][nt] = __builtin_amdgcn_mfma_f32_16x16x32_bf16(
                        afr[mi], bfr[nt], acc[mi][nt], 0, 0, 0);
        }
    }

    // ---- epilogue: noise + bias + leaky_relu * sqrt(2), fp32 store
    const int h = h0 + wr;
    const float nw = nw_p[0];
    float nz[4];
#pragma unroll
    for (int nt = 0; nt < 4; ++nt)
        nz[nt] = nw * noise[((size_t)b * Hh + h) * Ww + w0 + nt * 16 + l15];
#pragma unroll
    for (int mi = 0; mi < 2; ++mi) {
#pragma unroll
        for (int reg = 0; reg < 4; ++reg) {
            int co = (wm * 2 + mi) * 16 + quad * 4 + reg;
            float bias = act_bias[co];
#pragma unroll
            for (int nt = 0; nt < 4; ++nt) {
                float v = acc[mi][nt][reg] + nz[nt] + bias;
                v = (v > 0.f ? v : 0.2f * v) * 1.41421356237f;
                out[(((size_t)(b * Cc + co)) * Hh + h) * Ww + w0 + nt * 16 + l15] = v;
            }
        }
    }
}

extern "C" void kernel_launch(void* const* d_in, const int* in_sizes, int n_in,
                              void* d_out, int out_size, void* d_ws, size_t ws_size,
                              hipStream_t stream) {
    const float* x        = (const float*)d_in[0];
    const float* w        = (const float*)d_in[1];
    const float* noise    = (const float*)d_in[2];
    const float* lin_w    = (const float*)d_in[3];
    const float* lin_b    = (const float*)d_in[4];
    const float* conv_w   = (const float*)d_in[5];
    const float* nw_p     = (const float*)d_in[6];
    const float* act_bias = (const float*)d_in[7];

    float* y  = (float*)d_ws;                       // 512 floats
    short* wtb = (short*)((char*)d_ws + 4096);      // 8*2*9*64*32 bf16 = 576 KB

    k_style<<<Bn * Cc, 64, 0, stream>>>(w, lin_w, lin_b, y);
    k_weights<<<Bn * Cc, 64, 0, stream>>>(conv_w, y, wtb);

    k_mfma<<<dim3(2048, 1, 1), 512, 0, stream>>>(x, wtb, noise, nw_p, act_bias,
                                                 (float*)d_out);
}